// Round 5
// baseline (474.543 us; speedup 1.0000x reference)
//
#include <hip/hip_runtime.h>
#include <cstdint>
#include <cstddef>

#define BB   64
#define TT   512
#define CC   300
#define K1   256    // static max k for layer-1 kmax
#define RS   264    // padded ylds row: [4 zero | 256 data | 4 pad]
#define NG2  75     // fused groups: conv1 groups {2g,2g+1} + conv2 group g

__device__ __forceinline__ unsigned f2key(float f) {
    unsigned u = __float_as_uint(f);
    return (u & 0x80000000u) ? ~u : (u | 0x80000000u);   // monotone float->uint
}
__device__ __forceinline__ float key2f(unsigned k) {
    unsigned u = (k & 0x80000000u) ? (k & 0x7FFFFFFFu) : ~k;
    return __uint_as_float(u);
}
__device__ __forceinline__ float fast_tanh(float x) {
    float e = __expf(2.0f * x);
    return 1.0f - 2.0f * __builtin_amdgcn_rcpf(e + 1.0f);
}
__device__ __forceinline__ int mbcnt64(unsigned long long m) {
    return (int)__builtin_amdgcn_mbcnt_hi((unsigned)(m >> 32),
                 __builtin_amdgcn_mbcnt_lo((unsigned)m, 0u));
}

__global__ void init_out(const float* __restrict__ bfc, float* __restrict__ out) {
    int i = threadIdx.x;
    if (i < 2 * BB) out[i] = (i & 1) ? bfc[0] : 0.0f;
}

// ---------------- conv1 + dynamic k-max (layer 1), output into LDS row ----------------
// Lane owns S consecutive positions t = S*lane + j. Float-space bisection with
// count==k exit (exact); tie fallback. (Verified absmax 0.0 in R4.)
template<int S>
__device__ __forceinline__ void conv1_core(
    const float (* __restrict__ xs)[524], int lane, int n, int k,
    const float* wA, const float* wB, float br, float* __restrict__ row)
{
    constexpr int NV = (S == 8) ? 16 : 12;
    const int t0 = S * lane;

    float xa[NV], xb[NV];
    #pragma unroll
    for (int q = 0; q < NV / 4; ++q) {
        *(float4*)&xa[4 * q] = *(const float4*)&xs[0][t0 + 4 * q];
        *(float4*)&xb[4 * q] = *(const float4*)&xs[1][t0 + 4 * q];
    }

    float v[S + 1];
    #pragma unroll
    for (int j = 0; j < S; ++j) {
        float acc = br;
        #pragma unroll
        for (int kk = 0; kk < 7; ++kk)
            acc = fmaf(xa[j + kk], wA[kk], fmaf(xb[j + kk], wB[kk], acc));
        v[j] = (t0 + j < n) ? acc : -INFINITY;
    }
    v[S] = -INFINITY;
    if (S == 8 && n > 512) {                 // tail t = 512..517, lanes 0..5
        if (lane < 6 && 512 + lane < n) {
            float acc = br;
            #pragma unroll
            for (int kk = 0; kk < 7; ++kk)
                acc = fmaf(xs[0][512 + lane + kk], wA[kk],
                      fmaf(xs[1][512 + lane + kk], wB[kk], acc));
            v[S] = acc;
        }
    }

    float lmax = -INFINITY, lmin = INFINITY;
    #pragma unroll
    for (int j = 0; j <= S; ++j) {
        lmax = fmaxf(lmax, v[j]);
        lmin = fminf(lmin, (v[j] == -INFINITY) ? INFINITY : v[j]);
    }
    #pragma unroll
    for (int o = 32; o; o >>= 1) {
        lmax = fmaxf(lmax, __shfl_xor(lmax, o));
        lmin = fminf(lmin, __shfl_xor(lmin, o));
    }
    const float vmax = lmax, vmin = lmin;

    float tau; bool found = false;
    int cmax = 0;
    #pragma unroll
    for (int j = 0; j <= S; ++j) cmax += (int)__popcll(__ballot(v[j] == vmax));
    if (cmax >= k) {
        tau = vmax;
    } else {
        float lo = vmin, hi = vmax;          // inv: cnt(>=lo)>k, cnt(>=hi)<k
        tau = lo;
        while (true) {
            float mid = 0.5f * (lo + hi);
            if (mid == lo || mid == hi) { tau = lo; break; }
            int c = 0;
            #pragma unroll
            for (int j = 0; j <= S; ++j)
                c += (int)__popcll(__ballot(v[j] >= mid));
            if (c == k) { tau = mid; found = true; break; }
            if (c > k) lo = mid; else hi = mid;
        }
    }

    bool bG[S + 1], bE[S + 1];
    unsigned long long mG[S + 1], mE[S + 1];
    #pragma unroll
    for (int j = 0; j <= S; ++j) {
        bG[j] = found ? (v[j] >= tau) : (v[j] > tau);
        bE[j] = found ? false : (v[j] == tau);
        mG[j] = __ballot(bG[j]);
        mE[j] = __ballot(bE[j]);
    }
    int cg = 0;
    #pragma unroll
    for (int j = 0; j <= S; ++j) cg += (int)__popcll(mG[j]);
    const int budget = k - cg;

    int SGm = 0, SEm = 0, FGm = 0, FEm = 0;
    #pragma unroll
    for (int j = 0; j < S; ++j) {
        SGm += mbcnt64(mG[j]);  FGm += (int)__popcll(mG[j]);
        SEm += mbcnt64(mE[j]);  FEm += (int)__popcll(mE[j]);
    }
    int ownG = 0, ownE = 0;
    #pragma unroll
    for (int j = 0; j < S; ++j) {
        if (bG[j] || bE[j]) {
            int E = SEm + ownE;
            if (bG[j] || E < budget) {
                int pos = SGm + ownG + min(E, budget);
                row[4 + pos] = fast_tanh(v[j]);
            }
        }
        ownG += bG[j] ? 1 : 0;  ownE += bE[j] ? 1 : 0;
    }
    if (S == 8 && (bG[S] || bE[S])) {
        int E = FEm + mbcnt64(mE[S]);
        if (bG[S] || E < budget) {
            int pos = FGm + mbcnt64(mG[S]) + min(E, budget);
            row[4 + pos] = fast_tanh(v[S]);
        }
    }
    // zeros: head [0,4); tail [4+k, 4+k+8)∩[0,RS) — conv2 reads at most 4 past k,
    // and when k>=253 this also covers through RS.
    if (lane < 4) row[lane] = 0.0f;
    if (lane < 8) { int idx = 4 + k + lane; if (idx < RS) row[idx] = 0.0f; }
}

// ---------------- fused: conv1 -> kmax -> tanh -> conv2 -> kmax4 -> tanh -> fc ----------------
// One block per (g2, b); 6 waves. ylds never leaves the CU.
__global__ __launch_bounds__(384) void fused_dcnn(
    const float* __restrict__ x, const int* __restrict__ lengths,
    const float* __restrict__ w1, const float* __restrict__ b1,
    const float* __restrict__ w2, const float* __restrict__ b2,
    const float* __restrict__ wfc, float* __restrict__ out)
{
    const int g   = blockIdx.x;              // conv2 group, 0..74
    const int b   = blockIdx.y;
    const int tid = threadIdx.x;
    const int r   = tid >> 6, lane = tid & 63;
    const int len = lengths[b];
    const int n   = len + 6;
    const int k   = max(4, (len + 1) >> 1);
    const int n2  = k + 4;

    __shared__ __align__(16) float xs[4][524];     // input channels 4g..4g+3
    __shared__ __align__(16) float ylds[12][264];  // layer-1 output rows
    __shared__ float partial[6];

    for (int p = tid; p < 4 * 524; p += 384) {
        int ic = p / 524;
        int q  = p - ic * 524;
        int t  = q - 6;
        xs[ic][q] = (t >= 0 && t < len) ? x[((size_t)b * TT + t) * CC + 4 * g + ic] : 0.0f;
    }
    __syncthreads();

    // ---- phase 1: wave r does conv1 channel (2g+grp)*6+r for grp in {0,1} ----
    #pragma unroll
    for (int grp = 0; grp < 2; ++grp) {
        const float* wp = w1 + ((size_t)(2 * g + grp) * 6 + r) * 14;  // wave-uniform
        float wA[7], wB[7];
        #pragma unroll
        for (int i = 0; i < 7; ++i) { wA[i] = wp[i]; wB[i] = wp[7 + i]; }
        const float br = b1[(size_t)(2 * g + grp) * 6 + r];
        float* row = &ylds[grp * 6 + r][0];
        if (n <= 256) conv1_core<4>(&xs[2 * grp], lane, n, k, wA, wB, br, row);
        else          conv1_core<8>(&xs[2 * grp], lane, n, k, wA, wB, br, row);
    }
    __syncthreads();

    // ---- phase 2: conv2 + top-4 + tanh + fc. Wave r: channels r, r+6 (+ r+12 if r<2) ----
    const int nch = (r < 2) ? 3 : 2;
    const float* __restrict__ wg = w2 + (size_t)g * 840;

    float bias_s[3];
    #pragma unroll
    for (int it = 0; it < 3; ++it)
        bias_s[it] = (it < nch) ? b2[(size_t)g * 14 + (r + 6 * it)] : 0.0f;

    float acc[3][4];
    #pragma unroll
    for (int it = 0; it < 3; ++it)
        #pragma unroll
        for (int j = 0; j < 4; ++j) acc[it][j] = bias_s[it];

    for (int c = 0; c < 12; ++c) {
        const float4 f0 = *(const float4*)&ylds[c][4 * lane];
        const float4 f1 = *(const float4*)&ylds[c][4 * lane + 4];
        const float e[8] = {f0.x, f0.y, f0.z, f0.w, f1.x, f1.y, f1.z, f1.w};
        #pragma unroll
        for (int it = 0; it < 3; ++it) {
            if (it < nch) {
                const float* wp = wg + (r + 6 * it) * 60 + c * 5;     // scalar loads
                #pragma unroll
                for (int kw = 0; kw < 5; ++kw) {
                    const float q = wp[kw];
                    acc[it][0] = fmaf(e[0 + kw], q, acc[it][0]);
                    acc[it][1] = fmaf(e[1 + kw], q, acc[it][1]);
                    acc[it][2] = fmaf(e[2 + kw], q, acc[it][2]);
                    acc[it][3] = fmaf(e[3 + kw], q, acc[it][3]);
                }
            }
        }
    }

    float tval[3];
    #pragma unroll
    for (int it = 0; it < 3; ++it) tval[it] = -INFINITY;
    if (n2 > 256) {                          // tail positions 256..259 (k >= 253)
        if (lane < 4 && 256 + lane < n2) {
            const int w = 256 + lane;
            float ta[3];
            #pragma unroll
            for (int it = 0; it < 3; ++it) ta[it] = bias_s[it];
            for (int c = 0; c < 12; ++c) {
                #pragma unroll
                for (int kw = 0; kw < 5; ++kw) {
                    const float xv = ylds[c][w + kw];
                    #pragma unroll
                    for (int it = 0; it < 3; ++it)
                        if (it < nch)
                            ta[it] = fmaf(xv, wg[(r + 6 * it) * 60 + c * 5 + kw], ta[it]);
                }
            }
            #pragma unroll
            for (int it = 0; it < 3; ++it) tval[it] = ta[it];
        }
    }

    float fcsum = 0.0f;
    #pragma unroll
    for (int it = 0; it < 3; ++it) {
        if (it < nch) {
            const int r2 = r + 6 * it;       // wave-uniform
            unsigned kk[5];
            #pragma unroll
            for (int j = 0; j < 4; ++j)
                kk[j] = (4 * lane + j < n2) ? f2key(acc[it][j]) : 0u;
            kk[4] = (tval[it] != -INFINITY) ? f2key(tval[it]) : 0u;

            float tv[4]; int ti[4];
            #pragma unroll
            for (int round = 0; round < 4; ++round) {
                unsigned best = max(max(kk[0], kk[1]), max(kk[2], kk[3]));
                best = max(best, kk[4]);
                #pragma unroll
                for (int o = 32; o; o >>= 1)
                    best = max(best, (unsigned)__shfl_xor((int)best, o));
                int jm = 5;
                #pragma unroll
                for (int j = 4; j >= 0; --j) if (kk[j] == best) jm = j;
                unsigned long long m = __ballot(jm < 5);
                int wl;
                if (__popcll(m) == 1) {
                    wl = __ffsll((long long)m) - 1;
                } else {                     // exact value tie: smallest t wins
                    int myt = (jm == 4) ? (256 + lane)
                            : (jm < 4 ? 4 * lane + jm : 0x7FFFFFFF);
                    int tmin = myt;
                    #pragma unroll
                    for (int o = 32; o; o >>= 1) tmin = min(tmin, __shfl_xor(tmin, o));
                    wl = __ffsll((long long)__ballot(myt == tmin)) - 1;
                }
                const int jw = __shfl(jm, wl);
                ti[round] = (jw == 4) ? (256 + wl) : (4 * wl + jw);
                tv[round] = key2f(best);
                #pragma unroll
                for (int j = 0; j < 5; ++j)
                    if (lane == wl && jm == j) kk[j] = 0u;
            }
            #define CSW(a,bq) if (ti[a] > ti[bq]) { int t_=ti[a]; ti[a]=ti[bq]; ti[bq]=t_; float f_=tv[a]; tv[a]=tv[bq]; tv[bq]=f_; }
            CSW(0,1) CSW(2,3) CSW(0,2) CSW(1,3) CSW(1,2)
            #undef CSW

            const float* wfp = wfc + r2 * 75 + g;              // scalar loads
            float s = fast_tanh(tv[0]) * wfp[0];
            s = fmaf(fast_tanh(tv[1]), wfp[1050], s);
            s = fmaf(fast_tanh(tv[2]), wfp[2100], s);
            s = fmaf(fast_tanh(tv[3]), wfp[3150], s);
            fcsum += s;
        }
    }
    if (lane == 0) partial[r] = fcsum;
    __syncthreads();
    if (tid == 0) {
        float s = partial[0];
        #pragma unroll
        for (int i = 1; i < 6; ++i) s += partial[i];
        atomicAdd(&out[b * 2 + 1], s);
    }
}

extern "C" void kernel_launch(void* const* d_in, const int* in_sizes, int n_in,
                              void* d_out, int out_size, void* d_ws, size_t ws_size,
                              hipStream_t stream) {
    const float* x       = (const float*)d_in[0];
    const int*   lengths = (const int*)  d_in[1];
    const float* w1      = (const float*)d_in[2];
    const float* b1      = (const float*)d_in[3];
    const float* w2      = (const float*)d_in[4];
    const float* b2      = (const float*)d_in[5];
    const float* wfc     = (const float*)d_in[6];
    const float* bfc     = (const float*)d_in[7];
    float* out = (float*)d_out;

    init_out<<<dim3(1), dim3(128), 0, stream>>>(bfc, out);
    fused_dcnn<<<dim3(NG2, BB), dim3(384), 0, stream>>>(x, lengths, w1, b1, w2, b2, wfc, out);
}

// Round 6
// 320.514 us; speedup vs baseline: 1.4806x; 1.4806x over previous
//
#include <hip/hip_runtime.h>
#include <cstdint>
#include <cstddef>

#define BB   64
#define TT   512
#define CC   300
#define NG1  150    // conv1 groups (2 in-ch, 6 out-ch each)
#define OC1  900
#define K1   256    // static max k for layer-1 kmax
#define RS   264    // padded y1 row stride: [4 zero | 256 data | 4 zero]
#define NG2  75     // conv2 groups (12 y1 rows, 14 out-ch each)

__device__ __forceinline__ unsigned f2key(float f) {
    unsigned u = __float_as_uint(f);
    return (u & 0x80000000u) ? ~u : (u | 0x80000000u);   // monotone float->uint
}
__device__ __forceinline__ float key2f(unsigned k) {
    unsigned u = (k & 0x80000000u) ? (k & 0x7FFFFFFFu) : ~k;
    return __uint_as_float(u);
}
__device__ __forceinline__ float fast_tanh(float x) {
    float e = __expf(2.0f * x);
    return 1.0f - 2.0f * __builtin_amdgcn_rcpf(e + 1.0f);
}
__device__ __forceinline__ int mbcnt64(unsigned long long m) {
    return (int)__builtin_amdgcn_mbcnt_hi((unsigned)(m >> 32),
                 __builtin_amdgcn_mbcnt_lo((unsigned)m, 0u));
}

__global__ void init_out(const float* __restrict__ bfc, float* __restrict__ out) {
    int i = threadIdx.x;
    if (i < 2 * BB) out[i] = (i & 1) ? bfc[0] : 0.0f;
}

// ---------------- conv1 + dynamic k-max (layer 1) ----------------
// (Bit-identical to R4: verified absmax 0.0.)
template<int S>
__device__ __forceinline__ void conv1_core(
    const float (* __restrict__ xs)[524], int lane, int n, int k,
    const float* wA, const float* wB, float br, float* __restrict__ row)
{
    constexpr int NV = (S == 8) ? 16 : 12;
    const int t0 = S * lane;

    float xa[NV], xb[NV];
    #pragma unroll
    for (int q = 0; q < NV / 4; ++q) {
        *(float4*)&xa[4 * q] = *(const float4*)&xs[0][t0 + 4 * q];
        *(float4*)&xb[4 * q] = *(const float4*)&xs[1][t0 + 4 * q];
    }

    float v[S + 1];
    #pragma unroll
    for (int j = 0; j < S; ++j) {
        float acc = br;
        #pragma unroll
        for (int kk = 0; kk < 7; ++kk)
            acc = fmaf(xa[j + kk], wA[kk], fmaf(xb[j + kk], wB[kk], acc));
        v[j] = (t0 + j < n) ? acc : -INFINITY;
    }
    v[S] = -INFINITY;
    if (S == 8 && n > 512) {
        if (lane < 6 && 512 + lane < n) {
            float acc = br;
            #pragma unroll
            for (int kk = 0; kk < 7; ++kk)
                acc = fmaf(xs[0][512 + lane + kk], wA[kk],
                      fmaf(xs[1][512 + lane + kk], wB[kk], acc));
            v[S] = acc;
        }
    }

    float lmax = -INFINITY, lmin = INFINITY;
    #pragma unroll
    for (int j = 0; j <= S; ++j) {
        lmax = fmaxf(lmax, v[j]);
        lmin = fminf(lmin, (v[j] == -INFINITY) ? INFINITY : v[j]);
    }
    #pragma unroll
    for (int o = 32; o; o >>= 1) {
        lmax = fmaxf(lmax, __shfl_xor(lmax, o));
        lmin = fminf(lmin, __shfl_xor(lmin, o));
    }
    const float vmax = lmax, vmin = lmin;

    float tau; bool found = false;
    int cmax = 0;
    #pragma unroll
    for (int j = 0; j <= S; ++j) cmax += (int)__popcll(__ballot(v[j] == vmax));
    if (cmax >= k) {
        tau = vmax;
    } else {
        float lo = vmin, hi = vmax;          // inv: cnt(>=lo)>k, cnt(>=hi)<k
        tau = lo;
        while (true) {
            float mid = 0.5f * (lo + hi);
            if (mid == lo || mid == hi) { tau = lo; break; }
            int c = 0;
            #pragma unroll
            for (int j = 0; j <= S; ++j)
                c += (int)__popcll(__ballot(v[j] >= mid));
            if (c == k) { tau = mid; found = true; break; }
            if (c > k) lo = mid; else hi = mid;
        }
    }

    bool bG[S + 1], bE[S + 1];
    unsigned long long mG[S + 1], mE[S + 1];
    #pragma unroll
    for (int j = 0; j <= S; ++j) {
        bG[j] = found ? (v[j] >= tau) : (v[j] > tau);
        bE[j] = found ? false : (v[j] == tau);
        mG[j] = __ballot(bG[j]);
        mE[j] = __ballot(bE[j]);
    }
    int cg = 0;
    #pragma unroll
    for (int j = 0; j <= S; ++j) cg += (int)__popcll(mG[j]);
    const int budget = k - cg;

    int SGm = 0, SEm = 0, FGm = 0, FEm = 0;
    #pragma unroll
    for (int j = 0; j < S; ++j) {
        SGm += mbcnt64(mG[j]);  FGm += (int)__popcll(mG[j]);
        SEm += mbcnt64(mE[j]);  FEm += (int)__popcll(mE[j]);
    }
    int ownG = 0, ownE = 0;
    #pragma unroll
    for (int j = 0; j < S; ++j) {
        if (bG[j] || bE[j]) {
            int E = SEm + ownE;
            if (bG[j] || E < budget) {
                int pos = SGm + ownG + min(E, budget);
                row[4 + pos] = fast_tanh(v[j]);
            }
        }
        ownG += bG[j] ? 1 : 0;  ownE += bE[j] ? 1 : 0;
    }
    if (S == 8 && (bG[S] || bE[S])) {
        int E = FEm + mbcnt64(mE[S]);
        if (bG[S] || E < budget) {
            int pos = FGm + mbcnt64(mG[S]) + min(E, budget);
            row[4 + pos] = fast_tanh(v[S]);
        }
    }
    if (lane < 4) row[lane] = 0.0f;
    for (int w = k + lane; w < RS - 4; w += 64) row[4 + w] = 0.0f;
}

__global__ __launch_bounds__(384) void conv1_kmax(
    const float* __restrict__ x, const int* __restrict__ lengths,
    const float* __restrict__ w1, const float* __restrict__ b1,
    float* __restrict__ y1)
{
    const int g = blockIdx.x, b = blockIdx.y;
    const int tid = threadIdx.x;
    const int len = lengths[b];
    const int n = len + 6;
    const int k = max(4, (len + 1) >> 1);

    __shared__ __align__(16) float xs[2][524];
    __shared__ float ws[84];
    __shared__ float bs[6];
    if (tid < 84) ws[tid] = w1[g * 84 + tid];
    if (tid < 6)  bs[tid] = b1[g * 6 + tid];
    for (int p = tid; p < 1048; p += 384) {
        int ic = (p >= 524) ? 1 : 0;
        int q = p - ic * 524;
        int t = q - 6;
        xs[ic][q] = (t >= 0 && t < len) ? x[((size_t)b * TT + t) * CC + 2 * g + ic] : 0.0f;
    }
    __syncthreads();

    const int r = tid >> 6, lane = tid & 63;
    float wA[7], wB[7];
    #pragma unroll
    for (int i = 0; i < 7; ++i) { wA[i] = ws[r * 14 + i]; wB[i] = ws[r * 14 + 7 + i]; }
    const float br = bs[r];
    float* row = y1 + ((size_t)b * OC1 + g * 6 + r) * RS;

    if (n <= 256) conv1_core<4>(xs, lane, n, k, wA, wB, br, row);
    else          conv1_core<8>(xs, lane, n, k, wA, wB, br, row);
}

// ---------------- conv2 + k-max(4) + tanh + fc (fused) ----------------
// Latency fix vs R4: 12 row-loads split into 3 static batches of 4 with
// batch-level prefetch -> up to 16 float4 loads in flight; compute covers latency.
#define LOADB(F, cbase)                                                        \
    do {                                                                       \
        _Pragma("unroll")                                                      \
        for (int j_ = 0; j_ < 4; ++j_) {                                       \
            const float* rp_ = base + (size_t)((cbase) + j_) * RS + 4 * lane;  \
            F[2 * j_]     = *(const float4*)rp_;                               \
            F[2 * j_ + 1] = *(const float4*)(rp_ + 4);                         \
        }                                                                      \
    } while (0)

#define COMPB(F, cbase)                                                        \
    do {                                                                       \
        _Pragma("unroll")                                                      \
        for (int j_ = 0; j_ < 4; ++j_) {                                       \
            const int c_ = (cbase) + j_;                                       \
            const float e_[8] = {F[2*j_].x, F[2*j_].y, F[2*j_].z, F[2*j_].w,   \
                                 F[2*j_+1].x, F[2*j_+1].y, F[2*j_+1].z, F[2*j_+1].w}; \
            _Pragma("unroll")                                                  \
            for (int it_ = 0; it_ < 4; ++it_) {                                \
                if (it_ < nch) {                                               \
                    const float* wp_ = wg + (r2u0 + it_) * 60 + c_ * 5;        \
                    _Pragma("unroll")                                          \
                    for (int kw_ = 0; kw_ < 5; ++kw_) {                        \
                        const float q_ = wp_[kw_];                             \
                        acc[it_][0] = fmaf(e_[0 + kw_], q_, acc[it_][0]);      \
                        acc[it_][1] = fmaf(e_[1 + kw_], q_, acc[it_][1]);      \
                        acc[it_][2] = fmaf(e_[2 + kw_], q_, acc[it_][2]);      \
                        acc[it_][3] = fmaf(e_[3 + kw_], q_, acc[it_][3]);      \
                    }                                                          \
                }                                                              \
            }                                                                  \
        }                                                                      \
    } while (0)

__global__ __launch_bounds__(256) void conv2_kmax_fc(
    const float* __restrict__ y1, const int* __restrict__ lengths,
    const float* __restrict__ w2, const float* __restrict__ b2,
    const float* __restrict__ wfc, float* __restrict__ out)
{
    const int g = blockIdx.x, b = blockIdx.y;
    const int tid = threadIdx.x;
    const int wv = tid >> 6, lane = tid & 63;
    const int len = lengths[b];
    const int k1 = max(4, (len + 1) >> 1);
    const int n2 = k1 + 4;                   // valid conv2 prefix (<= 260)

    const int r2u0 = __builtin_amdgcn_readfirstlane(4 * wv);
    const int nch  = (wv == 3) ? 2 : 4;
    const float* __restrict__ wg = w2 + (size_t)g * 840;
    const float* base = y1 + ((size_t)b * OC1 + g * 12) * RS;

    float bias_s[4];
    #pragma unroll
    for (int it = 0; it < 4; ++it)
        bias_s[it] = (4 * wv + it < 14) ? b2[(size_t)g * 14 + r2u0 + it] : 0.0f;

    float acc[4][4];
    #pragma unroll
    for (int it = 0; it < 4; ++it)
        #pragma unroll
        for (int j = 0; j < 4; ++j) acc[it][j] = bias_s[it];

    // pipelined main conv: lane covers w = 4*lane .. 4*lane+3
    {
        float4 A[8], B[8];
        LOADB(A, 0);
        LOADB(B, 4);        // 16 loads in flight
        COMPB(A, 0);        // ~640 cy, covers B's latency
        LOADB(A, 8);        // issue last batch during B's compute
        COMPB(B, 4);
        COMPB(A, 8);
    }

    // tail positions w = 256..259 (only when n2 > 256; rare)
    float tval[4];
    #pragma unroll
    for (int it = 0; it < 4; ++it) tval[it] = -INFINITY;
    if (n2 > 256) {
        if (lane < 4 && 256 + lane < n2) {
            const int w = 256 + lane;
            float ta[4];
            #pragma unroll
            for (int it = 0; it < 4; ++it) ta[it] = bias_s[it];
            for (int c = 0; c < 12; ++c) {
                const float* rp = base + (size_t)c * RS;
                #pragma unroll
                for (int kw = 0; kw < 5; ++kw) {
                    const float xv = rp[w + kw];
                    #pragma unroll
                    for (int it = 0; it < 4; ++it)
                        if (it < nch)
                            ta[it] = fmaf(xv, wg[(r2u0 + it) * 60 + c * 5 + kw], ta[it]);
                }
            }
            #pragma unroll
            for (int it = 0; it < 4; ++it) tval[it] = ta[it];
        }
    }

    // per-channel: order-preserving top-4 -> tanh -> fc dot
    float fcsum = 0.0f;
    #pragma unroll
    for (int it = 0; it < 4; ++it) {
        if (it < nch) {
            unsigned kk[5];
            #pragma unroll
            for (int j = 0; j < 4; ++j)
                kk[j] = (4 * lane + j < n2) ? f2key(acc[it][j]) : 0u;
            kk[4] = (tval[it] != -INFINITY) ? f2key(tval[it]) : 0u;

            float tv[4]; int ti[4];
            #pragma unroll
            for (int round = 0; round < 4; ++round) {
                unsigned best = max(max(kk[0], kk[1]), max(kk[2], kk[3]));
                best = max(best, kk[4]);
                #pragma unroll
                for (int o = 32; o; o >>= 1)
                    best = max(best, (unsigned)__shfl_xor((int)best, o));
                int jm = 5;
                #pragma unroll
                for (int j = 4; j >= 0; --j) if (kk[j] == best) jm = j;
                unsigned long long m = __ballot(jm < 5);
                int wl;
                if (__popcll(m) == 1) {
                    wl = __ffsll((long long)m) - 1;
                } else {                      // exact value tie: smallest t wins
                    int myt = (jm == 4) ? (256 + lane)
                            : (jm < 4 ? 4 * lane + jm : 0x7FFFFFFF);
                    int tmin = myt;
                    #pragma unroll
                    for (int o = 32; o; o >>= 1) tmin = min(tmin, __shfl_xor(tmin, o));
                    wl = __ffsll((long long)__ballot(myt == tmin)) - 1;
                }
                const int jw = __shfl(jm, wl);
                ti[round] = (jw == 4) ? (256 + wl) : (4 * wl + jw);
                tv[round] = key2f(best);
                #pragma unroll
                for (int j = 0; j < 5; ++j)
                    if (lane == wl && jm == j) kk[j] = 0u;
            }
            #define CSW(a,bq) if (ti[a] > ti[bq]) { int t_=ti[a]; ti[a]=ti[bq]; ti[bq]=t_; float f_=tv[a]; tv[a]=tv[bq]; tv[bq]=f_; }
            CSW(0,1) CSW(2,3) CSW(0,2) CSW(1,3) CSW(1,2)
            #undef CSW

            const float* wfp = wfc + (r2u0 + it) * 75 + g;
            float s = fast_tanh(tv[0]) * wfp[0];
            s = fmaf(fast_tanh(tv[1]), wfp[1050], s);
            s = fmaf(fast_tanh(tv[2]), wfp[2100], s);
            s = fmaf(fast_tanh(tv[3]), wfp[3150], s);
            fcsum += s;
        }
    }
    if (lane == 0) atomicAdd(&out[b * 2 + 1], fcsum);
}

extern "C" void kernel_launch(void* const* d_in, const int* in_sizes, int n_in,
                              void* d_out, int out_size, void* d_ws, size_t ws_size,
                              hipStream_t stream) {
    const float* x       = (const float*)d_in[0];
    const int*   lengths = (const int*)  d_in[1];
    const float* w1      = (const float*)d_in[2];
    const float* b1      = (const float*)d_in[3];
    const float* w2      = (const float*)d_in[4];
    const float* b2      = (const float*)d_in[5];
    const float* wfc     = (const float*)d_in[6];
    const float* bfc     = (const float*)d_in[7];
    float* out = (float*)d_out;
    float* y1  = (float*)d_ws;      // [64][900][264] f32 = 60.8 MB padded rows

    init_out<<<dim3(1), dim3(128), 0, stream>>>(bfc, out);
    conv1_kmax<<<dim3(NG1, BB), dim3(384), 0, stream>>>(x, lengths, w1, b1, y1);
    conv2_kmax_fc<<<dim3(NG2, BB), dim3(256), 0, stream>>>(y1, lengths, w2, b2, wfc, out);
}